// Round 11
// baseline (150.691 us; speedup 1.0000x reference)
//
#include <hip/hip_runtime.h>
#include <math.h>

#define LOG2E 1.44269504088896340736f

typedef float f32x2 __attribute__((ext_vector_type(2)));
__device__ __forceinline__ f32x2 pkfma(f32x2 a, f32x2 b, f32x2 c) {
    return __builtin_elementwise_fma(a, b, c);
}
__device__ __forceinline__ f32x2 sp(float s) { f32x2 v = {s, s}; return v; }
__device__ __forceinline__ f32x2 lrelu2(f32x2 m) {
    return __builtin_elementwise_max(m, 0.2f * m);
}

// butterfly add via DPP (pure VALU, no LDS): xor1=quad_perm[1,0,3,2],
// xor2=quad_perm[2,3,0,1], 8-lane mirror = row_half_mirror
#define DPPADD(p, ctrl) \
    p += __int_as_float(__builtin_amdgcn_mov_dpp(__float_as_int(p), ctrl, 0xF, 0xF, true))
#define RED8(p) do { DPPADD(p, 0xB1); DPPADD(p, 0x4E); DPPADD(p, 0x141); } while (0)

// ---------------- CSR build: two-level counting sort (no global atomics) ----

__global__ void k_bcnt(const int* __restrict__ dst, int* __restrict__ cntmat,
                       int E, int CE, int NBK) {
    __shared__ int cnt[256];
    int t = threadIdx.x;
    cnt[t] = 0;
    __syncthreads();
    int c = blockIdx.x;
    int lo = c * CE, hi = min(E, lo + CE);
    for (int e = lo + t; e < hi; e += 256)
        atomicAdd(&cnt[dst[e] >> 8], 1);
    __syncthreads();
    if (t < NBK) cntmat[t * 256 + c] = cnt[t];
}

__global__ void k_scan1(const int* __restrict__ in, int* __restrict__ out,
                        int* __restrict__ blocksum, int L) {
    __shared__ int sm[256];
    int t = threadIdx.x;
    int i = blockIdx.x * 256 + t;
    int v = (i < L) ? in[i] : 0;
    sm[t] = v;
    __syncthreads();
    #pragma unroll
    for (int off = 1; off < 256; off <<= 1) {
        int add = (t >= off) ? sm[t - off] : 0;
        __syncthreads();
        sm[t] += add;
        __syncthreads();
    }
    if (i < L) out[i] = sm[t] - v;   // exclusive
    if (t == 255) blocksum[blockIdx.x] = sm[255];
}

__global__ void k_scan2(int* __restrict__ blocksum, int nb) {
    __shared__ int sm[256];
    int t = threadIdx.x;
    int v = (t < nb) ? blocksum[t] : 0;
    sm[t] = v;
    __syncthreads();
    #pragma unroll
    for (int off = 1; off < 256; off <<= 1) {
        int add = (t >= off) ? sm[t - off] : 0;
        __syncthreads();
        sm[t] += add;
        __syncthreads();
    }
    if (t < nb) blocksum[t] = sm[t] - v;
}

__global__ void k_scan3b(int* __restrict__ arr, const int* __restrict__ blocksum, int L) {
    int i = blockIdx.x * 256 + threadIdx.x;
    if (i < L) arr[i] += blocksum[blockIdx.x];
}

__global__ void k_part(const int* __restrict__ src, const int* __restrict__ dst,
                       const float* __restrict__ ea, const int* __restrict__ gofs,
                       int2* __restrict__ tmp, int E, int CE, int NBK) {
    __shared__ int cur[256];
    int t = threadIdx.x;
    int c = blockIdx.x;
    if (t < NBK) cur[t] = gofs[t * 256 + c];
    __syncthreads();
    int lo = c * CE, hi = min(E, lo + CE);
    for (int e = lo + t; e < hi; e += 256) {
        int d = dst[e];
        int pos = atomicAdd(&cur[d >> 8], 1);
        tmp[pos] = make_int2(((d & 255) << 24) | (src[e] << 4), __float_as_int(ea[e]));
    }
}

__global__ void k_fsort(const int2* __restrict__ tmp, const int* __restrict__ gofs,
                        int2* __restrict__ csr, int* __restrict__ row_ptr,
                        int N, int E, int NBK) {
    __shared__ int lcnt[256], lofs[256], lcur[256];
    int bkt = blockIdx.x;
    int t = threadIdx.x;
    int base = gofs[bkt * 256];
    int endv = (bkt == NBK - 1) ? E : gofs[(bkt + 1) * 256];
    int cnt = endv - base;
    lcnt[t] = 0;
    __syncthreads();
    for (int i = t; i < cnt; i += 256)
        atomicAdd(&lcnt[(unsigned)tmp[base + i].x >> 24], 1);
    __syncthreads();
    int v = lcnt[t];
    lofs[t] = v;
    __syncthreads();
    #pragma unroll
    for (int off = 1; off < 256; off <<= 1) {
        int add = (t >= off) ? lofs[t - off] : 0;
        __syncthreads();
        lofs[t] += add;
        __syncthreads();
    }
    int excl = lofs[t] - v;
    int nlo = bkt << 8;
    if (nlo + t < N) row_ptr[nlo + t] = base + excl;
    lcur[t] = base + excl;
    __syncthreads();
    for (int i = t; i < cnt; i += 256) {
        int2 e2 = tmp[base + i];
        int dl = (unsigned)e2.x >> 24;
        int pos = atomicAdd(&lcur[dl], 1);
        csr[pos] = make_int2(e2.x & 0x00FFFFFF, e2.y);
    }
    if (bkt == 0 && t == 0) row_ptr[N] = E;
}

__global__ void k_loopea(const int* __restrict__ row_ptr, const int2* __restrict__ csr,
                         float* __restrict__ loop_ea, int N) {
    int i = blockIdx.x * blockDim.x + threadIdx.x;
    if (i >= N) return;
    int start = row_ptr[i], end = row_ptr[i + 1];
    float s = 0.0f;
    for (int k = start; k < end; ++k) s += __int_as_float(csr[k].y);
    loop_ea[i] = s / fmaxf((float)(end - start), 1.0f);
}

// ---------------- layer 1 ----------------

// One wave per dst node, lane = 2 channels (packed f32x2 math -> v_pk_* ops).
// node wave-uniform via readfirstlane -> scalar s_loads in the loop.
__global__ void k_l1_node(const int2* __restrict__ csr, const int* __restrict__ row_ptr,
                          const float* __restrict__ x, const float* __restrict__ loop_ea,
                          const float* __restrict__ Wl1, const float* __restrict__ bl1,
                          const float* __restrict__ Wr1, const float* __restrict__ br1,
                          const float* __restrict__ We1, const float* __restrict__ att1,
                          const float* __restrict__ bias1, float* __restrict__ h1, int N) {
    int node = blockIdx.x * (blockDim.x >> 6) + (threadIdx.x >> 6);
    if (node >= N) return;
    node = __builtin_amdgcn_readfirstlane(node);
    int lane = threadIdx.x & 63;
    const f32x2* Wl1v = (const f32x2*)Wl1;
    f32x2 wl0 = Wl1v[lane],       wl1v = Wl1v[64 + lane];
    f32x2 wl2v = Wl1v[128 + lane], wl3v = Wl1v[192 + lane];
    f32x2 b2 = ((const f32x2*)bl1)[lane];
    float4 xv = *(const float4*)(x + (size_t)node * 4);
    const f32x2* Wr1v = (const f32x2*)Wr1;
    f32x2 rr = ((const f32x2*)br1)[lane];
    rr = pkfma(sp(xv.x), Wr1v[lane],       rr);
    rr = pkfma(sp(xv.y), Wr1v[64 + lane],  rr);
    rr = pkfma(sp(xv.z), Wr1v[128 + lane], rr);
    rr = pkfma(sp(xv.w), Wr1v[192 + lane], rr);
    f32x2 we2 = ((const f32x2*)We1)[lane];
    f32x2 at2 = ((const f32x2*)att1)[lane] * LOG2E;   // fold exp -> exp2
    const char* xb = (const char*)x;

    #define VL2(xs) pkfma(sp((xs).w), wl3v, pkfma(sp((xs).z), wl2v, \
                    pkfma(sp((xs).y), wl1v, pkfma(sp((xs).x), wl0, b2))))
    #define LOGIT(xs, ee, vl, aa) \
        f32x2 vl = VL2(xs); \
        float aa; \
        { f32x2 m_ = lrelu2(pkfma(sp(ee), we2, vl + rr)); \
          f32x2 q_ = m_ * at2; \
          float p_ = q_.x + q_.y; RED8(p_); aa = exp2f(p_); }

    int start = row_ptr[node];
    int deg   = row_ptr[node + 1] - start;
    const int2* crow = csr + start;

    // self-loop
    float eav = loop_ea[node];
    LOGIT(xv, eav, vls, a);
    float den = a;
    f32x2 acc = sp(a) * vls;
    int k = 0;
    for (; k + 4 <= deg; k += 4) {
        int2 pr0 = crow[k],     pr1 = crow[k + 1];
        int2 pr2 = crow[k + 2], pr3 = crow[k + 3];
        float e0 = __int_as_float(pr0.y), e1 = __int_as_float(pr1.y);
        float e2 = __int_as_float(pr2.y), e3 = __int_as_float(pr3.y);
        float4 x0 = *(const float4*)(xb + (unsigned)pr0.x);
        float4 x1 = *(const float4*)(xb + (unsigned)pr1.x);
        float4 x2 = *(const float4*)(xb + (unsigned)pr2.x);
        float4 x3 = *(const float4*)(xb + (unsigned)pr3.x);
        LOGIT(x0, e0, vl0, a0);
        LOGIT(x1, e1, vl1, a1);
        LOGIT(x2, e2, vl2, a2);
        LOGIT(x3, e3, vl3, a3);
        den += (a0 + a1) + (a2 + a3);
        acc = pkfma(sp(a0), vl0, acc);
        acc = pkfma(sp(a1), vl1, acc);
        acc = pkfma(sp(a2), vl2, acc);
        acc = pkfma(sp(a3), vl3, acc);
    }
    for (; k < deg; ++k) {
        int2 pr = crow[k];
        float ee = __int_as_float(pr.y);
        float4 xs = *(const float4*)(xb + (unsigned)pr.x);
        LOGIT(xs, ee, vls2, aa);
        den += aa;
        acc = pkfma(sp(aa), vls2, acc);
    }
    #undef VL2
    #undef LOGIT
    f32x2 bia = ((const f32x2*)bias1)[lane];
    f32x2 o = pkfma(acc, sp(1.0f / den), bia);
    float o0 = o.x > 0.0f ? o.x : expm1f(o.x);
    float o1 = o.y > 0.0f ? o.y : expm1f(o.y);
    *(float2*)(h1 + (size_t)node * 128 + lane * 2) = make_float2(o0, o1);
}

// ---------------- layer 2 ----------------

// interleave Wl2/Wr2 -> Wint[k*8+j] = (Wl2[k][j], Wr2[k][j])
__global__ void k_wint(const float* __restrict__ Wl2, const float* __restrict__ Wr2,
                       float2* __restrict__ Wint) {
    int t = blockIdx.x * blockDim.x + threadIdx.x;
    if (t < 1024) Wint[t] = make_float2(Wl2[t], Wr2[t]);
}

// thread = (node, j): packed (l,r) dot via interleaved weights
__global__ void k_l2_lin(const float* __restrict__ h1, const f32x2* __restrict__ Wint,
                         const float* __restrict__ bl2, const float* __restrict__ br2,
                         float* __restrict__ xl2, float* __restrict__ xr2, int N) {
    int t = blockIdx.x * blockDim.x + threadIdx.x;
    if (t >= N * 8) return;
    int i = t >> 3, j = t & 7;
    f32x2 acc = {bl2[j], br2[j]};
    const float* row = h1 + (size_t)i * 128;
    #pragma unroll 4
    for (int k = 0; k < 128; k += 4) {
        float4 hv = *(const float4*)(row + k);
        acc = pkfma(sp(hv.x), Wint[k * 8 + j],       acc);
        acc = pkfma(sp(hv.y), Wint[(k + 1) * 8 + j], acc);
        acc = pkfma(sp(hv.z), Wint[(k + 2) * 8 + j], acc);
        acc = pkfma(sp(hv.w), Wint[(k + 3) * 8 + j], acc);
    }
    xl2[t] = acc.x;
    xr2[t] = acc.y;
}

// 8 lanes per dst node, lane = edge within group. Per-lane local accumulation;
// single deferred 9-value DPP reduce per node (sums are linear).
__global__ void k_l2_node(const int2* __restrict__ csr, const int* __restrict__ row_ptr,
                          const float* __restrict__ xl2, const float* __restrict__ xr2,
                          const float* __restrict__ loop_ea,
                          const float* __restrict__ We2, const float* __restrict__ att2,
                          const float* __restrict__ bias2, float* __restrict__ h2, int N) {
    int t = blockIdx.x * blockDim.x + threadIdx.x;
    int node = t >> 3;
    int lane = t & 7;
    if (node >= N) return;
    float4 ra = *(const float4*)(xr2 + (size_t)node * 8);
    float4 rb = *(const float4*)(xr2 + (size_t)node * 8 + 4);
    f32x2 rv0 = {ra.x, ra.y}, rv1 = {ra.z, ra.w}, rv2 = {rb.x, rb.y}, rv3 = {rb.z, rb.w};
    f32x2 we0 = ((const f32x2*)We2)[0], we1 = ((const f32x2*)We2)[1];
    f32x2 we2v = ((const f32x2*)We2)[2], we3 = ((const f32x2*)We2)[3];
    f32x2 at0 = ((const f32x2*)att2)[0] * LOG2E, at1 = ((const f32x2*)att2)[1] * LOG2E;
    f32x2 at2v = ((const f32x2*)att2)[2] * LOG2E, at3 = ((const f32x2*)att2)[3] * LOG2E;
    const char* xlb = (const char*)xl2;
    int start = row_ptr[node], deg = row_ptr[node + 1] - start;
    int total = deg + 1;          // + self loop
    float den = 0.0f;
    f32x2 ac0 = {0,0}, ac1 = {0,0}, ac2 = {0,0}, ac3 = {0,0};
    for (int base = 0; base < total; base += 8) {
        int e = base + lane;
        if (e < total) {
            const float* lp;
            float eav;
            if (e < deg) {
                int2 pr = csr[start + e];
                lp = (const float*)(xlb + 2u * (unsigned)pr.x);   // src*32 bytes
                eav = __int_as_float(pr.y);
            } else {
                lp = xl2 + (size_t)node * 8;
                eav = loop_ea[node];
            }
            float4 la = *(const float4*)lp;
            float4 lb = *(const float4*)(lp + 4);
            f32x2 l0 = {la.x, la.y}, l1 = {la.z, la.w};
            f32x2 l2 = {lb.x, lb.y}, l3 = {lb.z, lb.w};
            f32x2 ev = sp(eav);
            f32x2 q = lrelu2(pkfma(ev, we0, l0 + rv0)) * at0;
            q = pkfma(lrelu2(pkfma(ev, we1, l1 + rv1)), at1, q);
            q = pkfma(lrelu2(pkfma(ev, we2v, l2 + rv2)), at2v, q);
            q = pkfma(lrelu2(pkfma(ev, we3, l3 + rv3)), at3, q);
            float a = exp2f(q.x + q.y);
            den += a;
            f32x2 av = sp(a);
            ac0 = pkfma(av, l0, ac0);
            ac1 = pkfma(av, l1, ac1);
            ac2 = pkfma(av, l2, ac2);
            ac3 = pkfma(av, l3, ac3);
        }
    }
    // single deferred reduction across the 8-lane group
    RED8(den);
    float w0 = ac0.x, w1 = ac0.y, w2 = ac1.x, w3 = ac1.y;
    float w4 = ac2.x, w5 = ac2.y, w6 = ac3.x, w7 = ac3.y;
    RED8(w0); RED8(w1); RED8(w2); RED8(w3);
    RED8(w4); RED8(w5); RED8(w6); RED8(w7);
    if (lane == 0) {
        float inv = 1.0f / den;
        float o[8] = {w0, w1, w2, w3, w4, w5, w6, w7};
        #pragma unroll
        for (int cc = 0; cc < 8; ++cc) {
            float v = fmaf(o[cc], inv, bias2[cc]);
            o[cc] = v > 0.0f ? v : expm1f(v);
        }
        *(float4*)(h2 + (size_t)node * 8)     = make_float4(o[0], o[1], o[2], o[3]);
        *(float4*)(h2 + (size_t)node * 8 + 4) = make_float4(o[4], o[5], o[6], o[7]);
    }
}

// One block per graph; batch is sorted -> binary-search the segment.
__global__ void k_pool(const float* __restrict__ h2, const int* __restrict__ batch,
                       const float* __restrict__ W3, const float* __restrict__ b3,
                       float* __restrict__ out, int N) {
    int g = blockIdx.x;
    int lo = 0, hi = N;
    while (lo < hi) { int mid = (lo + hi) >> 1; if (batch[mid] < g) lo = mid + 1; else hi = mid; }
    int start = lo;
    int lo2 = start, hi2 = N;
    while (lo2 < hi2) { int mid = (lo2 + hi2) >> 1; if (batch[mid] < g + 1) lo2 = mid + 1; else hi2 = mid; }
    int end = lo2;
    int cnt = end - start;
    int t = threadIdx.x;
    int c = t & 7, rg = t >> 3;
    float s = 0.0f;
    for (int i = start + rg; i < end; i += 32) s += h2[(size_t)i * 8 + c];
    __shared__ float sm[256];
    sm[t] = s;
    __syncthreads();
    #pragma unroll
    for (int off = 16; off >= 1; off >>= 1) {
        if (rg < off) sm[t] += sm[t + off * 8];
        __syncthreads();
    }
    if (t == 0) {
        float inv = 1.0f / fmaxf((float)cnt, 1.0f);
        float acc = b3[0];
        #pragma unroll
        for (int cc = 0; cc < 8; ++cc) acc = fmaf(sm[cc] * inv, W3[cc], acc);
        out[g] = acc;
    }
}

extern "C" void kernel_launch(void* const* d_in, const int* in_sizes, int n_in,
                              void* d_out, int out_size, void* d_ws, size_t ws_size,
                              hipStream_t stream) {
    const float* x     = (const float*)d_in[0];
    const int*   ei    = (const int*)d_in[1];
    const float* ea    = (const float*)d_in[2];
    const int*   batch = (const int*)d_in[3];
    const float* Wl1 = (const float*)d_in[4];
    const float* bl1 = (const float*)d_in[5];
    const float* Wr1 = (const float*)d_in[6];
    const float* br1 = (const float*)d_in[7];
    const float* We1 = (const float*)d_in[8];
    const float* att1 = (const float*)d_in[9];
    const float* bias1 = (const float*)d_in[10];
    const float* Wl2 = (const float*)d_in[11];
    const float* bl2 = (const float*)d_in[12];
    const float* Wr2 = (const float*)d_in[13];
    const float* br2 = (const float*)d_in[14];
    const float* We2 = (const float*)d_in[15];
    const float* att2 = (const float*)d_in[16];
    const float* bias2 = (const float*)d_in[17];
    const float* W3 = (const float*)d_in[18];
    const float* b3 = (const float*)d_in[19];

    const int N  = in_sizes[0] / 4;
    const int E  = in_sizes[1] / 2;
    const int G  = out_size;
    const int* src = ei;
    const int* dst = ei + E;

    const int NBK = (N + 255) >> 8;          // buckets of 256 nodes, <= 256
    const int NCH = 256;                     // edge chunks
    const int CE  = (E + NCH - 1) / NCH;     // edges per chunk
    const int L   = NBK * 256;               // count-matrix length
    const int nbN = (N + 255) / 256;

    #define ALIGN4(v) (((v) + 3) & ~3)
    int* w = (int*)d_ws;
    int* gofs     = w; w += ALIGN4(L + 1);
    int* blocksum = w; w += 256;
    int* row_ptr  = w; w += ALIGN4(N + 1);
    float* loop_ea = (float*)w; w += ALIGN4(N);
    float* h1  = (float*)w; w += (size_t)N * 128;
    float* xl2 = (float*)w; w += (size_t)N * 8;
    float* xr2 = (float*)w; w += (size_t)N * 8;
    float2* Wint = (float2*)w; w += 2048;
    int2* tmp = (int2*)w; w += (size_t)E * 2;
    int2* csr = (int2*)w; w += (size_t)E * 2;
    float* h2 = h1;                          // h1 dead after k_l2_lin
    #undef ALIGN4

    // CSR build: two-level counting sort
    k_bcnt<<<NCH, 256, 0, stream>>>(dst, gofs, E, CE, NBK);
    k_scan1<<<NBK, 256, 0, stream>>>(gofs, gofs, blocksum, L);
    k_scan2<<<1, 256, 0, stream>>>(blocksum, NBK);
    k_scan3b<<<NBK, 256, 0, stream>>>(gofs, blocksum, L);
    k_part<<<NCH, 256, 0, stream>>>(src, dst, ea, gofs, tmp, E, CE, NBK);
    k_fsort<<<NBK, 256, 0, stream>>>(tmp, gofs, csr, row_ptr, N, E, NBK);
    k_loopea<<<nbN, 256, 0, stream>>>(row_ptr, csr, loop_ea, N);
    k_wint<<<4, 256, 0, stream>>>(Wl2, Wr2, Wint);

    // layer 1
    k_l1_node<<<(N + 3) / 4, 256, 0, stream>>>(csr, row_ptr, x, loop_ea,
                                               Wl1, bl1, Wr1, br1, We1, att1, bias1, h1, N);
    // layer 2
    k_l2_lin<<<((size_t)N * 8 + 255) / 256, 256, 0, stream>>>(h1, (const f32x2*)Wint,
                                                              bl2, br2, xl2, xr2, N);
    k_l2_node<<<((size_t)N * 8 + 255) / 256, 256, 0, stream>>>(csr, row_ptr, xl2, xr2,
                                                               loop_ea, We2, att2, bias2, h2, N);
    // pool + final linear
    k_pool<<<G, 256, 0, stream>>>(h2, batch, W3, b3, (float*)d_out, N);
}

// Round 12
// 137.767 us; speedup vs baseline: 1.0938x; 1.0938x over previous
//
#include <hip/hip_runtime.h>
#include <math.h>

#define LOG2E 1.44269504088896340736f

typedef float f32x2 __attribute__((ext_vector_type(2)));
__device__ __forceinline__ f32x2 pkfma(f32x2 a, f32x2 b, f32x2 c) {
    return __builtin_elementwise_fma(a, b, c);
}
__device__ __forceinline__ f32x2 sp(float s) { f32x2 v = {s, s}; return v; }
__device__ __forceinline__ f32x2 lrelu2(f32x2 m) {
    return __builtin_elementwise_max(m, 0.2f * m);
}
// raw v_exp_f32 (single inst). exp2f() takes OCML's denorm-safe path (~6 inst,
// 2 transcendentals); our logits are O(1) so the raw op is numerically identical.
__device__ __forceinline__ float fexp2(float x) {
    float r;
    asm("v_exp_f32 %0, %1" : "=v"(r) : "v"(x));
    return r;
}

// butterfly add via DPP (pure VALU, no LDS): xor1=quad_perm[1,0,3,2],
// xor2=quad_perm[2,3,0,1], 8-lane mirror = row_half_mirror
#define DPPADD(p, ctrl) \
    p += __int_as_float(__builtin_amdgcn_mov_dpp(__float_as_int(p), ctrl, 0xF, 0xF, true))
#define RED8(p) do { DPPADD(p, 0xB1); DPPADD(p, 0x4E); DPPADD(p, 0x141); } while (0)

// ---------------- CSR build: two-level counting sort (no global atomics) ----

__global__ void k_bcnt(const int* __restrict__ dst, int* __restrict__ cntmat,
                       int E, int CE, int NBK) {
    __shared__ int cnt[256];
    int t = threadIdx.x;
    cnt[t] = 0;
    __syncthreads();
    int c = blockIdx.x;
    int lo = c * CE, hi = min(E, lo + CE);
    for (int e = lo + t; e < hi; e += 256)
        atomicAdd(&cnt[dst[e] >> 8], 1);
    __syncthreads();
    if (t < NBK) cntmat[t * 256 + c] = cnt[t];
}

__global__ void k_scan1(const int* __restrict__ in, int* __restrict__ out,
                        int* __restrict__ blocksum, int L) {
    __shared__ int sm[256];
    int t = threadIdx.x;
    int i = blockIdx.x * 256 + t;
    int v = (i < L) ? in[i] : 0;
    sm[t] = v;
    __syncthreads();
    #pragma unroll
    for (int off = 1; off < 256; off <<= 1) {
        int add = (t >= off) ? sm[t - off] : 0;
        __syncthreads();
        sm[t] += add;
        __syncthreads();
    }
    if (i < L) out[i] = sm[t] - v;   // exclusive (block-local)
    if (t == 255) blocksum[blockIdx.x] = sm[255];
}

// scan block totals in place; idle threads also build the interleaved W2 table
__global__ void k_scan2(int* __restrict__ blocksum, int nb,
                        const float* __restrict__ Wl2, const float* __restrict__ Wr2,
                        float2* __restrict__ Wint) {
    __shared__ int sm[256];
    int t = threadIdx.x;
    int v = (t < nb) ? blocksum[t] : 0;
    sm[t] = v;
    __syncthreads();
    #pragma unroll
    for (int off = 1; off < 256; off <<= 1) {
        int add = (t >= off) ? sm[t - off] : 0;
        __syncthreads();
        sm[t] += add;
        __syncthreads();
    }
    if (t < nb) blocksum[t] = sm[t] - v;
    #pragma unroll
    for (int i = 0; i < 4; ++i)
        Wint[t + i * 256] = make_float2(Wl2[t + i * 256], Wr2[t + i * 256]);
}

// partition edges into bucket regions (block offsets folded in here)
__global__ void k_part(const int* __restrict__ src, const int* __restrict__ dst,
                       const float* __restrict__ ea, const int* __restrict__ gofs,
                       const int* __restrict__ blocksum,
                       int2* __restrict__ tmp, int E, int CE, int NBK) {
    __shared__ int cur[256];
    int t = threadIdx.x;
    int c = blockIdx.x;
    if (t < NBK) cur[t] = gofs[t * 256 + c] + blocksum[t];
    __syncthreads();
    int lo = c * CE, hi = min(E, lo + CE);
    for (int e = lo + t; e < hi; e += 256) {
        int d = dst[e];
        int pos = atomicAdd(&cur[d >> 8], 1);
        tmp[pos] = make_int2(((d & 255) << 24) | (src[e] << 4), __float_as_int(ea[e]));
    }
}

// fine sort within bucket; also emits row_ptr AND loop_ea (fused)
__global__ void k_fsort(const int2* __restrict__ tmp, const int* __restrict__ gofs,
                        const int* __restrict__ blocksum,
                        int2* __restrict__ csr, int* __restrict__ row_ptr,
                        float* __restrict__ loop_ea, int N, int E, int NBK) {
    __shared__ int lcnt[256], lofs[256], lcur[256];
    __shared__ float lea[256];
    int bkt = blockIdx.x;
    int t = threadIdx.x;
    int base = gofs[bkt * 256] + blocksum[bkt];
    int endv = (bkt == NBK - 1) ? E : (gofs[(bkt + 1) * 256] + blocksum[bkt + 1]);
    int cnt = endv - base;
    lcnt[t] = 0;
    lea[t] = 0.0f;
    __syncthreads();
    for (int i = t; i < cnt; i += 256) {
        int2 e2 = tmp[base + i];
        unsigned dl = (unsigned)e2.x >> 24;
        atomicAdd(&lcnt[dl], 1);
        atomicAdd(&lea[dl], __int_as_float(e2.y));
    }
    __syncthreads();
    int v = lcnt[t];
    lofs[t] = v;
    __syncthreads();
    #pragma unroll
    for (int off = 1; off < 256; off <<= 1) {
        int add = (t >= off) ? lofs[t - off] : 0;
        __syncthreads();
        lofs[t] += add;
        __syncthreads();
    }
    int excl = lofs[t] - v;
    int nlo = bkt << 8;
    if (nlo + t < N) {
        row_ptr[nlo + t] = base + excl;
        loop_ea[nlo + t] = lea[t] / fmaxf((float)v, 1.0f);
    }
    lcur[t] = base + excl;
    __syncthreads();
    for (int i = t; i < cnt; i += 256) {
        int2 e2 = tmp[base + i];
        int dl = (unsigned)e2.x >> 24;
        int pos = atomicAdd(&lcur[dl], 1);
        csr[pos] = make_int2(e2.x & 0x00FFFFFF, e2.y);
    }
    if (bkt == 0 && t == 0) row_ptr[N] = E;
}

// ---------------- layer 1 ----------------

// One wave per dst node, lane = 2 channels (packed f32x2 math).
// node wave-uniform via readfirstlane -> scalar s_loads in the loop; x8 unroll.
__global__ void k_l1_node(const int2* __restrict__ csr, const int* __restrict__ row_ptr,
                          const float* __restrict__ x, const float* __restrict__ loop_ea,
                          const float* __restrict__ Wl1, const float* __restrict__ bl1,
                          const float* __restrict__ Wr1, const float* __restrict__ br1,
                          const float* __restrict__ We1, const float* __restrict__ att1,
                          const float* __restrict__ bias1, float* __restrict__ h1, int N) {
    int node = blockIdx.x * (blockDim.x >> 6) + (threadIdx.x >> 6);
    if (node >= N) return;
    node = __builtin_amdgcn_readfirstlane(node);
    int lane = threadIdx.x & 63;
    const f32x2* Wl1v = (const f32x2*)Wl1;
    f32x2 wl0 = Wl1v[lane],        wl1v = Wl1v[64 + lane];
    f32x2 wl2v = Wl1v[128 + lane], wl3v = Wl1v[192 + lane];
    f32x2 b2 = ((const f32x2*)bl1)[lane];
    float4 xv = *(const float4*)(x + (size_t)node * 4);
    const f32x2* Wr1v = (const f32x2*)Wr1;
    f32x2 rr = ((const f32x2*)br1)[lane];
    rr = pkfma(sp(xv.x), Wr1v[lane],       rr);
    rr = pkfma(sp(xv.y), Wr1v[64 + lane],  rr);
    rr = pkfma(sp(xv.z), Wr1v[128 + lane], rr);
    rr = pkfma(sp(xv.w), Wr1v[192 + lane], rr);
    f32x2 we2 = ((const f32x2*)We1)[lane];
    f32x2 at2 = ((const f32x2*)att1)[lane] * LOG2E;   // fold exp -> exp2
    const char* xb = (const char*)x;

    #define VL2(xs) pkfma(sp((xs).w), wl3v, pkfma(sp((xs).z), wl2v, \
                    pkfma(sp((xs).y), wl1v, pkfma(sp((xs).x), wl0, b2))))
    #define LOGIT(xs, ee, vl, aa) \
        f32x2 vl = VL2(xs); \
        float aa; \
        { f32x2 m_ = lrelu2(pkfma(sp(ee), we2, vl + rr)); \
          f32x2 q_ = m_ * at2; \
          float p_ = q_.x + q_.y; RED8(p_); aa = fexp2(p_); }

    int start = row_ptr[node];
    int deg   = row_ptr[node + 1] - start;
    const int2* crow = csr + start;

    // self-loop
    float eav = loop_ea[node];
    LOGIT(xv, eav, vls, a);
    float den = a;
    f32x2 acc = sp(a) * vls;
    int k = 0;
    for (; k + 8 <= deg; k += 8) {
        int2 q0 = crow[k],     q1 = crow[k + 1], q2 = crow[k + 2], q3 = crow[k + 3];
        int2 q4 = crow[k + 4], q5 = crow[k + 5], q6 = crow[k + 6], q7 = crow[k + 7];
        float4 y0 = *(const float4*)(xb + (unsigned)q0.x);
        float4 y1 = *(const float4*)(xb + (unsigned)q1.x);
        float4 y2 = *(const float4*)(xb + (unsigned)q2.x);
        float4 y3 = *(const float4*)(xb + (unsigned)q3.x);
        float4 y4 = *(const float4*)(xb + (unsigned)q4.x);
        float4 y5 = *(const float4*)(xb + (unsigned)q5.x);
        float4 y6 = *(const float4*)(xb + (unsigned)q6.x);
        float4 y7 = *(const float4*)(xb + (unsigned)q7.x);
        LOGIT(y0, __int_as_float(q0.y), ul0, b0);
        LOGIT(y1, __int_as_float(q1.y), ul1, b1);
        LOGIT(y2, __int_as_float(q2.y), ul2, bb2);
        LOGIT(y3, __int_as_float(q3.y), ul3, b3);
        LOGIT(y4, __int_as_float(q4.y), ul4, b4);
        LOGIT(y5, __int_as_float(q5.y), ul5, b5);
        LOGIT(y6, __int_as_float(q6.y), ul6, b6);
        LOGIT(y7, __int_as_float(q7.y), ul7, b7);
        den += ((b0 + b1) + (bb2 + b3)) + ((b4 + b5) + (b6 + b7));
        acc = pkfma(sp(b0), ul0, acc);
        acc = pkfma(sp(b1), ul1, acc);
        acc = pkfma(sp(bb2), ul2, acc);
        acc = pkfma(sp(b3), ul3, acc);
        acc = pkfma(sp(b4), ul4, acc);
        acc = pkfma(sp(b5), ul5, acc);
        acc = pkfma(sp(b6), ul6, acc);
        acc = pkfma(sp(b7), ul7, acc);
    }
    for (; k + 4 <= deg; k += 4) {
        int2 pr0 = crow[k],     pr1 = crow[k + 1];
        int2 pr2 = crow[k + 2], pr3 = crow[k + 3];
        float4 x0 = *(const float4*)(xb + (unsigned)pr0.x);
        float4 x1 = *(const float4*)(xb + (unsigned)pr1.x);
        float4 x2 = *(const float4*)(xb + (unsigned)pr2.x);
        float4 x3 = *(const float4*)(xb + (unsigned)pr3.x);
        LOGIT(x0, __int_as_float(pr0.y), vl0, a0);
        LOGIT(x1, __int_as_float(pr1.y), vl1, a1);
        LOGIT(x2, __int_as_float(pr2.y), vl2, a2);
        LOGIT(x3, __int_as_float(pr3.y), vl3, a3);
        den += (a0 + a1) + (a2 + a3);
        acc = pkfma(sp(a0), vl0, acc);
        acc = pkfma(sp(a1), vl1, acc);
        acc = pkfma(sp(a2), vl2, acc);
        acc = pkfma(sp(a3), vl3, acc);
    }
    for (; k < deg; ++k) {
        int2 pr = crow[k];
        float4 xs = *(const float4*)(xb + (unsigned)pr.x);
        LOGIT(xs, __int_as_float(pr.y), vls2, aa);
        den += aa;
        acc = pkfma(sp(aa), vls2, acc);
    }
    #undef VL2
    #undef LOGIT
    f32x2 bia = ((const f32x2*)bias1)[lane];
    f32x2 o = pkfma(acc, sp(1.0f / den), bia);
    float o0 = o.x > 0.0f ? o.x : expm1f(o.x);
    float o1 = o.y > 0.0f ? o.y : expm1f(o.y);
    *(float2*)(h1 + (size_t)node * 128 + lane * 2) = make_float2(o0, o1);
}

// ---------------- layer 2 ----------------

// thread = (node, j): packed (l,r) dot via interleaved weights
__global__ void k_l2_lin(const float* __restrict__ h1, const f32x2* __restrict__ Wint,
                         const float* __restrict__ bl2, const float* __restrict__ br2,
                         float* __restrict__ xl2, float* __restrict__ xr2, int N) {
    int t = blockIdx.x * blockDim.x + threadIdx.x;
    if (t >= N * 8) return;
    int i = t >> 3, j = t & 7;
    f32x2 acc = {bl2[j], br2[j]};
    const float* row = h1 + (size_t)i * 128;
    #pragma unroll 4
    for (int k = 0; k < 128; k += 4) {
        float4 hv = *(const float4*)(row + k);
        acc = pkfma(sp(hv.x), Wint[k * 8 + j],       acc);
        acc = pkfma(sp(hv.y), Wint[(k + 1) * 8 + j], acc);
        acc = pkfma(sp(hv.z), Wint[(k + 2) * 8 + j], acc);
        acc = pkfma(sp(hv.w), Wint[(k + 3) * 8 + j], acc);
    }
    xl2[t] = acc.x;
    xr2[t] = acc.y;
}

// 8 lanes per dst node, lane = edge within group. Per-lane local accumulation;
// single deferred 9-value DPP reduce per node (sums are linear).
__global__ void k_l2_node(const int2* __restrict__ csr, const int* __restrict__ row_ptr,
                          const float* __restrict__ xl2, const float* __restrict__ xr2,
                          const float* __restrict__ loop_ea,
                          const float* __restrict__ We2, const float* __restrict__ att2,
                          const float* __restrict__ bias2, float* __restrict__ h2, int N) {
    int t = blockIdx.x * blockDim.x + threadIdx.x;
    int node = t >> 3;
    int lane = t & 7;
    if (node >= N) return;
    float4 ra = *(const float4*)(xr2 + (size_t)node * 8);
    float4 rb = *(const float4*)(xr2 + (size_t)node * 8 + 4);
    f32x2 rv0 = {ra.x, ra.y}, rv1 = {ra.z, ra.w}, rv2 = {rb.x, rb.y}, rv3 = {rb.z, rb.w};
    f32x2 we0 = ((const f32x2*)We2)[0], we1 = ((const f32x2*)We2)[1];
    f32x2 we2v = ((const f32x2*)We2)[2], we3 = ((const f32x2*)We2)[3];
    f32x2 at0 = ((const f32x2*)att2)[0] * LOG2E, at1 = ((const f32x2*)att2)[1] * LOG2E;
    f32x2 at2v = ((const f32x2*)att2)[2] * LOG2E, at3 = ((const f32x2*)att2)[3] * LOG2E;
    const char* xlb = (const char*)xl2;
    int start = row_ptr[node], deg = row_ptr[node + 1] - start;
    int total = deg + 1;          // + self loop
    float den = 0.0f;
    f32x2 ac0 = {0,0}, ac1 = {0,0}, ac2 = {0,0}, ac3 = {0,0};
    for (int base = 0; base < total; base += 8) {
        int e = base + lane;
        if (e < total) {
            const float* lp;
            float eav;
            if (e < deg) {
                int2 pr = csr[start + e];
                lp = (const float*)(xlb + 2u * (unsigned)pr.x);   // src*32 bytes
                eav = __int_as_float(pr.y);
            } else {
                lp = xl2 + (size_t)node * 8;
                eav = loop_ea[node];
            }
            float4 la = *(const float4*)lp;
            float4 lb = *(const float4*)(lp + 4);
            f32x2 l0 = {la.x, la.y}, l1 = {la.z, la.w};
            f32x2 l2 = {lb.x, lb.y}, l3 = {lb.z, lb.w};
            f32x2 ev = sp(eav);
            f32x2 q = lrelu2(pkfma(ev, we0, l0 + rv0)) * at0;
            q = pkfma(lrelu2(pkfma(ev, we1, l1 + rv1)), at1, q);
            q = pkfma(lrelu2(pkfma(ev, we2v, l2 + rv2)), at2v, q);
            q = pkfma(lrelu2(pkfma(ev, we3, l3 + rv3)), at3, q);
            float a = fexp2(q.x + q.y);
            den += a;
            f32x2 av = sp(a);
            ac0 = pkfma(av, l0, ac0);
            ac1 = pkfma(av, l1, ac1);
            ac2 = pkfma(av, l2, ac2);
            ac3 = pkfma(av, l3, ac3);
        }
    }
    // single deferred reduction across the 8-lane group
    RED8(den);
    float w0 = ac0.x, w1 = ac0.y, w2 = ac1.x, w3 = ac1.y;
    float w4 = ac2.x, w5 = ac2.y, w6 = ac3.x, w7 = ac3.y;
    RED8(w0); RED8(w1); RED8(w2); RED8(w3);
    RED8(w4); RED8(w5); RED8(w6); RED8(w7);
    if (lane == 0) {
        float inv = 1.0f / den;
        float o[8] = {w0, w1, w2, w3, w4, w5, w6, w7};
        #pragma unroll
        for (int cc = 0; cc < 8; ++cc) {
            float v = fmaf(o[cc], inv, bias2[cc]);
            o[cc] = v > 0.0f ? v : expm1f(v);
        }
        *(float4*)(h2 + (size_t)node * 8)     = make_float4(o[0], o[1], o[2], o[3]);
        *(float4*)(h2 + (size_t)node * 8 + 4) = make_float4(o[4], o[5], o[6], o[7]);
    }
}

// One block per graph; batch is sorted -> binary-search the segment.
__global__ void k_pool(const float* __restrict__ h2, const int* __restrict__ batch,
                       const float* __restrict__ W3, const float* __restrict__ b3,
                       float* __restrict__ out, int N) {
    int g = blockIdx.x;
    int lo = 0, hi = N;
    while (lo < hi) { int mid = (lo + hi) >> 1; if (batch[mid] < g) lo = mid + 1; else hi = mid; }
    int start = lo;
    int lo2 = start, hi2 = N;
    while (lo2 < hi2) { int mid = (lo2 + hi2) >> 1; if (batch[mid] < g + 1) lo2 = mid + 1; else hi2 = mid; }
    int end = lo2;
    int cnt = end - start;
    int t = threadIdx.x;
    int c = t & 7, rg = t >> 3;
    float s = 0.0f;
    for (int i = start + rg; i < end; i += 32) s += h2[(size_t)i * 8 + c];
    __shared__ float sm[256];
    sm[t] = s;
    __syncthreads();
    #pragma unroll
    for (int off = 16; off >= 1; off >>= 1) {
        if (rg < off) sm[t] += sm[t + off * 8];
        __syncthreads();
    }
    if (t == 0) {
        float inv = 1.0f / fmaxf((float)cnt, 1.0f);
        float acc = b3[0];
        #pragma unroll
        for (int cc = 0; cc < 8; ++cc) acc = fmaf(sm[cc] * inv, W3[cc], acc);
        out[g] = acc;
    }
}

extern "C" void kernel_launch(void* const* d_in, const int* in_sizes, int n_in,
                              void* d_out, int out_size, void* d_ws, size_t ws_size,
                              hipStream_t stream) {
    const float* x     = (const float*)d_in[0];
    const int*   ei    = (const int*)d_in[1];
    const float* ea    = (const float*)d_in[2];
    const int*   batch = (const int*)d_in[3];
    const float* Wl1 = (const float*)d_in[4];
    const float* bl1 = (const float*)d_in[5];
    const float* Wr1 = (const float*)d_in[6];
    const float* br1 = (const float*)d_in[7];
    const float* We1 = (const float*)d_in[8];
    const float* att1 = (const float*)d_in[9];
    const float* bias1 = (const float*)d_in[10];
    const float* Wl2 = (const float*)d_in[11];
    const float* bl2 = (const float*)d_in[12];
    const float* Wr2 = (const float*)d_in[13];
    const float* br2 = (const float*)d_in[14];
    const float* We2 = (const float*)d_in[15];
    const float* att2 = (const float*)d_in[16];
    const float* bias2 = (const float*)d_in[17];
    const float* W3 = (const float*)d_in[18];
    const float* b3 = (const float*)d_in[19];

    const int N  = in_sizes[0] / 4;
    const int E  = in_sizes[1] / 2;
    const int G  = out_size;
    const int* src = ei;
    const int* dst = ei + E;

    const int NBK = (N + 255) >> 8;          // buckets of 256 nodes, <= 256
    const int NCH = 256;                     // edge chunks
    const int CE  = (E + NCH - 1) / NCH;     // edges per chunk
    const int L   = NBK * 256;               // count-matrix length

    #define ALIGN4(v) (((v) + 3) & ~3)
    int* w = (int*)d_ws;
    int* gofs     = w; w += ALIGN4(L + 1);
    int* blocksum = w; w += 256;
    int* row_ptr  = w; w += ALIGN4(N + 1);
    float* loop_ea = (float*)w; w += ALIGN4(N);
    float* h1  = (float*)w; w += (size_t)N * 128;
    float* xl2 = (float*)w; w += (size_t)N * 8;
    float* xr2 = (float*)w; w += (size_t)N * 8;
    float2* Wint = (float2*)w; w += 2048;
    int2* tmp = (int2*)w; w += (size_t)E * 2;
    int2* csr = (int2*)w; w += (size_t)E * 2;
    float* h2 = h1;                          // h1 dead after k_l2_lin
    #undef ALIGN4

    // CSR build: two-level counting sort (block-offset add folded into consumers)
    k_bcnt<<<NCH, 256, 0, stream>>>(dst, gofs, E, CE, NBK);
    k_scan1<<<NBK, 256, 0, stream>>>(gofs, gofs, blocksum, L);
    k_scan2<<<1, 256, 0, stream>>>(blocksum, NBK, Wl2, Wr2, Wint);
    k_part<<<NCH, 256, 0, stream>>>(src, dst, ea, gofs, blocksum, tmp, E, CE, NBK);
    k_fsort<<<NBK, 256, 0, stream>>>(tmp, gofs, blocksum, csr, row_ptr, loop_ea, N, E, NBK);

    // layer 1
    k_l1_node<<<(N + 3) / 4, 256, 0, stream>>>(csr, row_ptr, x, loop_ea,
                                               Wl1, bl1, Wr1, br1, We1, att1, bias1, h1, N);
    // layer 2
    k_l2_lin<<<((size_t)N * 8 + 255) / 256, 256, 0, stream>>>(h1, (const f32x2*)Wint,
                                                              bl2, br2, xl2, xr2, N);
    k_l2_node<<<((size_t)N * 8 + 255) / 256, 256, 0, stream>>>(csr, row_ptr, xl2, xr2,
                                                               loop_ea, We2, att2, bias2, h2, N);
    // pool + final linear
    k_pool<<<G, 256, 0, stream>>>(h2, batch, W3, b3, (float*)d_out, N);
}